// Round 21
// baseline (84.195 us; speedup 1.0000x reference)
//
#include <hip/hip_runtime.h>
#include <hip/hip_bf16.h>

#define DIM 32
#define LOG_NPB 7
#define NPB 128              // nodes per bucket
#define CAP 4096             // edge capacity per bucket (avg ~2046)
#define NBINS 800            // >= ceil(100000/128)=782
#define EPB 16384            // edges per scatter block
#define EPT 16               // edges per thread in scatter (EPB/1024)
#define SG_THREADS 1024      // sort_gather block size (16 waves)
#define SG_WAVES 16

// ---------------------------------------------------------------------------
// Kernel 1: y = x @ W1^T (bf16 packed) ONLY. W1 row held in registers.
// Block 0 also inits bucket cursors (absolute: cursor[b] = b*CAP).
// ---------------------------------------------------------------------------
__global__ __launch_bounds__(256) void lin_y_kernel(
    const float* __restrict__ x,
    const float* __restrict__ W1,
    unsigned* __restrict__ y32,
    int* __restrict__ cursor, int nb,
    int n_nodes)
{
    __shared__ float xs[8][DIM];

    const int t = threadIdx.x;
    if (blockIdx.x == 0) {
        for (int i = t; i < nb; i += 256) cursor[i] = i * CAP;
    }

    const int r = t >> 5;
    const int c = t & 31;

    float4 w1r[8];
    #pragma unroll
    for (int q = 0; q < 8; ++q)
        w1r[q] = *(const float4*)(W1 + c * DIM + q * 4);

    const int ntiles = (n_nodes + 7) >> 3;

    for (int tile = blockIdx.x; tile < ntiles; tile += gridDim.x) {
        const int row = tile * 8 + r;
        __syncthreads();
        if (row < n_nodes) xs[r][c] = x[(long)row * DIM + c];
        __syncthreads();
        if (row < n_nodes) {
            const float4* xr = (const float4*)xs[r];
            float a1 = 0.0f;
            #pragma unroll
            for (int q = 0; q < 8; ++q) {
                float4 xv = xr[q];
                a1 += xv.x * w1r[q].x + xv.y * w1r[q].y + xv.z * w1r[q].z + xv.w * w1r[q].w;
            }
            float hi = __shfl_down(a1, 1);
            if ((c & 1) == 0) {
                __hip_bfloat16 blo = __float2bfloat16(a1);
                __hip_bfloat16 bhi = __float2bfloat16(hi);
                unsigned pack = ((unsigned)(*(unsigned short*)&bhi) << 16)
                              | (unsigned)(*(unsigned short*)&blo);
                y32[(size_t)row * 16 + (c >> 1)] = pack;
            }
        }
    }
}

// ---------------------------------------------------------------------------
// Pass 1: bucket scatter (r13/r17 proven shape: 98 fat blocks, rank merged
// into histogram atomic).
// ---------------------------------------------------------------------------
__global__ __launch_bounds__(1024) void bucket_scatter_kernel(
    const int* __restrict__ src, const int* __restrict__ dst,
    int* __restrict__ cursor, unsigned* __restrict__ bedges, int nE)
{
    __shared__ int cnt[NBINS];
    __shared__ int base[NBINS];

    const int t = threadIdx.x;
    const long blockStart = (long)blockIdx.x * EPB;

    for (int i = t; i < NBINS; i += 1024) cnt[i] = 0;
    __syncthreads();

    int es[EPT], ed[EPT], rk[EPT];
    #pragma unroll
    for (int i = 0; i < EPT; ++i) {
        long e = blockStart + (long)i * 1024 + t;
        if (e < nE) { es[i] = src[e]; ed[i] = dst[e]; }
        else        { es[i] = -1;     ed[i] = 0;      }
    }
    #pragma unroll
    for (int i = 0; i < EPT; ++i) {
        if (es[i] >= 0) rk[i] = atomicAdd(&cnt[ed[i] >> LOG_NPB], 1);
    }
    __syncthreads();

    for (int i = t; i < NBINS; i += 1024) {
        int c = cnt[i];
        if (c > 0) base[i] = atomicAdd(&cursor[i], c);
    }
    __syncthreads();

    #pragma unroll
    for (int i = 0; i < EPT; ++i) {
        if (es[i] >= 0) {
            int b = ed[i] >> LOG_NPB;
            int p = base[b] + rk[i];
            if (p < (b + 1) * CAP)
                bedges[p] = ((unsigned)es[i] << LOG_NPB) | (unsigned)(ed[i] & (NPB - 1));
        }
    }
}

// ---------------------------------------------------------------------------
// Pass 2 (fused): per-bucket LDS sort + pipelined gather + W2 skip-connection.
// NOW 1024 threads = 16 waves: each wave walks only 8 nodes sequentially
// (halves exposed per-node latency); occupancy -> ~32 waves/CU.
// Lane (slot,li) holds W2^T tile in 16 regs; x row prefetched in pipeline.
// out written exactly once per node (no RMW).
// ---------------------------------------------------------------------------
__global__ __launch_bounds__(SG_THREADS) void sort_gather_kernel(
    const int* __restrict__ cursor, const unsigned* __restrict__ bedges,
    const unsigned short* __restrict__ yb,
    const float* __restrict__ x,
    const float* __restrict__ W2,
    const float* __restrict__ b2,
    float* __restrict__ out, int n_nodes)
{
    __shared__ unsigned ent[CAP];      // 16 KB raw entries
    __shared__ unsigned sorted[CAP];   // 16 KB src ids sorted by local dst
    __shared__ int cnt[NPB];
    __shared__ int ex[NPB];
    __shared__ int cur[NPB];

    const int b = blockIdx.x;
    const int t = threadIdx.x;
    const int wv   = t >> 6;      // wave 0..15
    const int lane = t & 63;
    const int slot = lane >> 3;   // 0..7: edge slot / k-quad
    const int li   = lane & 7;    // output dims li*4..li*4+3

    // per-lane W2^T tile + bias
    float w2t[4][4];
    #pragma unroll
    for (int j = 0; j < 4; ++j)
        #pragma unroll
        for (int k = 0; k < 4; ++k)
            w2t[k][j] = W2[(size_t)(4 * li + j) * DIM + 4 * slot + k];
    const float4 bias = ((const float4*)b2)[li];

    const int start = b * CAP;
    int n = cursor[b] - start;
    if (n > CAP) n = CAP;
    if (n < 0) n = 0;

    if (t < NPB) { cnt[t] = 0; cur[t] = 0; }
    __syncthreads();

    for (int i = t; i < n; i += SG_THREADS) {
        unsigned e = bedges[start + i];
        ent[i] = e;
        atomicAdd(&cnt[e & (NPB - 1)], 1);
    }
    __syncthreads();

    // single-wave exclusive scan over 128 bins (2 bins/lane, no barriers)
    if (t < 64) {
        int c0 = cnt[2 * t];
        int c1 = cnt[2 * t + 1];
        int v  = c0 + c1;
        #pragma unroll
        for (int off = 1; off < 64; off <<= 1) {
            int u = __shfl_up(v, off);
            if (t >= off) v += u;
        }
        int pbase = v - (c0 + c1);
        ex[2 * t]     = pbase;
        ex[2 * t + 1] = pbase + c0;
    }
    __syncthreads();

    for (int i = t; i < n; i += SG_THREADS) {
        unsigned e = ent[i];
        int bin = (int)(e & (NPB - 1));
        int r = atomicAdd(&cur[bin], 1);
        sorted[ex[bin] + r] = e >> LOG_NPB;
    }
    __syncthreads();

    // ---- pipelined gather + skip phase ----
    int ln   = wv;
    int node = b * NPB + ln;
    if (node >= n_nodes) return;

    int st = ex[ln];
    int d  = cnt[ln];
    int s[4];
    #pragma unroll
    for (int k = 0; k < 4; ++k) {
        int e = slot + 8 * k;
        int idx = (e < d) ? e : (d > 0 ? d - 1 : 0);
        s[k] = (int)sorted[(d > 0 ? st : 0) + idx];
    }
    float4 xv = ((const float4*)(x + ((size_t)node << 5)))[slot];

    while (true) {
        // issue current node's y loads (chunk k only if 8k < d, wave-uniform)
        ushort4 u[4];
        #pragma unroll
        for (int k = 0; k < 4; ++k) {
            if (8 * k < d)
                u[k] = *(const ushort4*)(yb + ((size_t)s[k] << 5) + (li << 2));
        }

        // prefetch next node's state while y loads are in flight
        const int ln_n   = ln + SG_WAVES;
        const int node_n = node + SG_WAVES;
        const bool have_n = (ln_n < NPB) && (node_n < n_nodes);
        int st_n = 0, d_n = 0;
        int sn[4];
        float4 xv_n = make_float4(0.f, 0.f, 0.f, 0.f);
        if (have_n) {
            st_n = ex[ln_n];
            d_n  = cnt[ln_n];
            #pragma unroll
            for (int k = 0; k < 4; ++k) {
                int e = slot + 8 * k;
                int idx = (e < d_n) ? e : (d_n > 0 ? d_n - 1 : 0);
                sn[k] = (int)sorted[(d_n > 0 ? st_n : 0) + idx];
            }
            xv_n = ((const float4*)(x + ((size_t)node_n << 5)))[slot];
        }

        // W2 matvec partials (k in [4slot,4slot+4)) — VALU under load shadow
        float a0, a1, a2, a3;
        a0 = xv.x * w2t[0][0] + xv.y * w2t[1][0] + xv.z * w2t[2][0] + xv.w * w2t[3][0];
        a1 = xv.x * w2t[0][1] + xv.y * w2t[1][1] + xv.z * w2t[2][1] + xv.w * w2t[3][1];
        a2 = xv.x * w2t[0][2] + xv.y * w2t[1][2] + xv.z * w2t[2][2] + xv.w * w2t[3][2];
        a3 = xv.x * w2t[0][3] + xv.y * w2t[1][3] + xv.z * w2t[2][3] + xv.w * w2t[3][3];

        // gather adds
        #pragma unroll
        for (int k = 0; k < 4; ++k) {
            if (8 * k < d) {
                const bool v = (slot + 8 * k) < d;
                a0 += v ? __uint_as_float((unsigned)u[k].x << 16) : 0.f;
                a1 += v ? __uint_as_float((unsigned)u[k].y << 16) : 0.f;
                a2 += v ? __uint_as_float((unsigned)u[k].z << 16) : 0.f;
                a3 += v ? __uint_as_float((unsigned)u[k].w << 16) : 0.f;
            }
        }
        // rare tail: degree > 32
        for (int e0 = 32 + slot; e0 < d; e0 += 8) {
            int ss = (int)sorted[st + e0];
            ushort4 uu = *(const ushort4*)(yb + ((size_t)ss << 5) + (li << 2));
            a0 += __uint_as_float((unsigned)uu.x << 16);
            a1 += __uint_as_float((unsigned)uu.y << 16);
            a2 += __uint_as_float((unsigned)uu.z << 16);
            a3 += __uint_as_float((unsigned)uu.w << 16);
        }

        #pragma unroll
        for (int m = 8; m < 64; m <<= 1) {
            a0 += __shfl_xor(a0, m);
            a1 += __shfl_xor(a1, m);
            a2 += __shfl_xor(a2, m);
            a3 += __shfl_xor(a3, m);
        }

        if (slot == 0) {
            float4 w;
            w.x = a0 + bias.x;
            w.y = a1 + bias.y;
            w.z = a2 + bias.z;
            w.w = a3 + bias.w;
            ((float4*)(out + ((size_t)node << 5)))[li] = w;   // single write, no RMW
        }

        if (!have_n) break;
        ln = ln_n; node = node_n; st = st_n; d = d_n;
        s[0] = sn[0]; s[1] = sn[1]; s[2] = sn[2]; s[3] = sn[3];
        xv = xv_n;
    }
}

extern "C" void kernel_launch(void* const* d_in, const int* in_sizes, int n_in,
                              void* d_out, int out_size, void* d_ws, size_t ws_size,
                              hipStream_t stream) {
    const float* x  = (const float*)d_in[0];
    const float* W1 = (const float*)d_in[1];
    const float* W2 = (const float*)d_in[2];
    const float* b2 = (const float*)d_in[3];
    const int*   ei = (const int*)d_in[4];

    const int n_nodes = in_sizes[0] / DIM;   // 100000
    const int n_edges = in_sizes[4] / 2;     // 1,600,000
    const int* src = ei;
    const int* dst = ei + n_edges;
    float* out = (float*)d_out;

    const int nb = (n_nodes + NPB - 1) / NPB;    // 782

    char* basep = (char*)d_ws;
    size_t off = 0;
    auto alloc = [&](size_t bytes) {
        char* p = basep + off;
        off = (off + bytes + 255) & ~(size_t)255;
        return p;
    };
    unsigned* y32    = (unsigned*)alloc((size_t)n_nodes * DIM * sizeof(unsigned short));
    int*      cursor = (int*)     alloc((size_t)nb * sizeof(int));
    unsigned* bedges = (unsigned*)alloc((size_t)nb * CAP * sizeof(unsigned));
    (void)ws_size;

    lin_y_kernel<<<1024, 256, 0, stream>>>(x, W1, y32, cursor, nb, n_nodes);
    bucket_scatter_kernel<<<(n_edges + EPB - 1) / EPB, 1024, 0, stream>>>(src, dst, cursor, bedges, n_edges);
    sort_gather_kernel<<<nb, SG_THREADS, 0, stream>>>(cursor, bedges, (const unsigned short*)y32,
                                                      x, W2, b2, out, n_nodes);
}

// Round 22
// 81.472 us; speedup vs baseline: 1.0334x; 1.0334x over previous
//
#include <hip/hip_runtime.h>
#include <hip/hip_bf16.h>

#define DIM 32
#define LOG_NPB 7
#define NPB 128              // nodes per bucket
#define CAP 4096             // edge capacity per bucket (avg ~2046)
#define NBINS 800            // >= ceil(100000/128)=782
#define EPB 16384            // edges per scatter block
#define EPT 16               // edges per thread in scatter (EPB/1024)

// ---------------------------------------------------------------------------
// Kernel 1: y = x @ W1^T (bf16 packed) ONLY. W1 row held in registers.
// Block 0 also inits bucket cursors (absolute: cursor[b] = b*CAP).
// ---------------------------------------------------------------------------
__global__ __launch_bounds__(256) void lin_y_kernel(
    const float* __restrict__ x,
    const float* __restrict__ W1,
    unsigned* __restrict__ y32,
    int* __restrict__ cursor, int nb,
    int n_nodes)
{
    __shared__ float xs[8][DIM];

    const int t = threadIdx.x;
    if (blockIdx.x == 0) {
        for (int i = t; i < nb; i += 256) cursor[i] = i * CAP;
    }

    const int r = t >> 5;
    const int c = t & 31;

    float4 w1r[8];
    #pragma unroll
    for (int q = 0; q < 8; ++q)
        w1r[q] = *(const float4*)(W1 + c * DIM + q * 4);

    const int ntiles = (n_nodes + 7) >> 3;

    for (int tile = blockIdx.x; tile < ntiles; tile += gridDim.x) {
        const int row = tile * 8 + r;
        __syncthreads();
        if (row < n_nodes) xs[r][c] = x[(long)row * DIM + c];
        __syncthreads();
        if (row < n_nodes) {
            const float4* xr = (const float4*)xs[r];
            float a1 = 0.0f;
            #pragma unroll
            for (int q = 0; q < 8; ++q) {
                float4 xv = xr[q];
                a1 += xv.x * w1r[q].x + xv.y * w1r[q].y + xv.z * w1r[q].z + xv.w * w1r[q].w;
            }
            float hi = __shfl_down(a1, 1);
            if ((c & 1) == 0) {
                __hip_bfloat16 blo = __float2bfloat16(a1);
                __hip_bfloat16 bhi = __float2bfloat16(hi);
                unsigned pack = ((unsigned)(*(unsigned short*)&bhi) << 16)
                              | (unsigned)(*(unsigned short*)&blo);
                y32[(size_t)row * 16 + (c >> 1)] = pack;
            }
        }
    }
}

// ---------------------------------------------------------------------------
// Pass 1: bucket scatter (r13/r17 proven shape: 98 fat blocks, rank merged
// into histogram atomic).
// ---------------------------------------------------------------------------
__global__ __launch_bounds__(1024) void bucket_scatter_kernel(
    const int* __restrict__ src, const int* __restrict__ dst,
    int* __restrict__ cursor, unsigned* __restrict__ bedges, int nE)
{
    __shared__ int cnt[NBINS];
    __shared__ int base[NBINS];

    const int t = threadIdx.x;
    const long blockStart = (long)blockIdx.x * EPB;

    for (int i = t; i < NBINS; i += 1024) cnt[i] = 0;
    __syncthreads();

    int es[EPT], ed[EPT], rk[EPT];
    #pragma unroll
    for (int i = 0; i < EPT; ++i) {
        long e = blockStart + (long)i * 1024 + t;
        if (e < nE) { es[i] = src[e]; ed[i] = dst[e]; }
        else        { es[i] = -1;     ed[i] = 0;      }
    }
    #pragma unroll
    for (int i = 0; i < EPT; ++i) {
        if (es[i] >= 0) rk[i] = atomicAdd(&cnt[ed[i] >> LOG_NPB], 1);
    }
    __syncthreads();

    for (int i = t; i < NBINS; i += 1024) {
        int c = cnt[i];
        if (c > 0) base[i] = atomicAdd(&cursor[i], c);
    }
    __syncthreads();

    #pragma unroll
    for (int i = 0; i < EPT; ++i) {
        if (es[i] >= 0) {
            int b = ed[i] >> LOG_NPB;
            int p = base[b] + rk[i];
            if (p < (b + 1) * CAP)
                bedges[p] = ((unsigned)es[i] << LOG_NPB) | (unsigned)(ed[i] & (NPB - 1));
        }
    }
}

// ---------------------------------------------------------------------------
// Pass 2 (fused): per-bucket LDS sort + 2-DEEP pipelined gather + W2 skip.
// 512 threads = 8 waves, each walking 16 nodes. Node n+1's y loads are
// ISSUED during iteration n (indices prefetched earlier), giving each y
// batch a full iteration of latency cover. out written once, no RMW.
// ---------------------------------------------------------------------------
__global__ __launch_bounds__(512) void sort_gather_kernel(
    const int* __restrict__ cursor, const unsigned* __restrict__ bedges,
    const unsigned short* __restrict__ yb,
    const float* __restrict__ x,
    const float* __restrict__ W2,
    const float* __restrict__ b2,
    float* __restrict__ out, int n_nodes)
{
    __shared__ unsigned ent[CAP];      // 16 KB raw entries
    __shared__ unsigned sorted[CAP];   // 16 KB src ids sorted by local dst
    __shared__ int cnt[NPB];
    __shared__ int ex[NPB];
    __shared__ int cur[NPB];

    const int b = blockIdx.x;
    const int t = threadIdx.x;
    const int wv   = t >> 6;      // wave 0..7
    const int lane = t & 63;
    const int slot = lane >> 3;   // 0..7: edge slot / k-quad
    const int li   = lane & 7;    // output dims li*4..li*4+3

    // per-lane W2^T tile + bias
    float w2t[4][4];
    #pragma unroll
    for (int j = 0; j < 4; ++j)
        #pragma unroll
        for (int k = 0; k < 4; ++k)
            w2t[k][j] = W2[(size_t)(4 * li + j) * DIM + 4 * slot + k];
    const float4 bias = ((const float4*)b2)[li];

    const int start = b * CAP;
    int n = cursor[b] - start;
    if (n > CAP) n = CAP;
    if (n < 0) n = 0;

    if (t < NPB) { cnt[t] = 0; cur[t] = 0; }
    __syncthreads();

    for (int i = t; i < n; i += 512) {
        unsigned e = bedges[start + i];
        ent[i] = e;
        atomicAdd(&cnt[e & (NPB - 1)], 1);
    }
    __syncthreads();

    // single-wave exclusive scan over 128 bins (2 bins/lane, no barriers)
    if (t < 64) {
        int c0 = cnt[2 * t];
        int c1 = cnt[2 * t + 1];
        int v  = c0 + c1;
        #pragma unroll
        for (int off = 1; off < 64; off <<= 1) {
            int u = __shfl_up(v, off);
            if (t >= off) v += u;
        }
        int pbase = v - (c0 + c1);
        ex[2 * t]     = pbase;
        ex[2 * t + 1] = pbase + c0;
    }
    __syncthreads();

    for (int i = t; i < n; i += 512) {
        unsigned e = ent[i];
        int bin = (int)(e & (NPB - 1));
        int r = atomicAdd(&cur[bin], 1);
        sorted[ex[bin] + r] = e >> LOG_NPB;
    }
    __syncthreads();

    // ---- 2-deep pipelined gather + skip phase ----
    int ln   = wv;
    int node = b * NPB + ln;
    if (node >= n_nodes) return;

    // prologue: node state + ISSUE its y loads
    int st = ex[ln];
    int d  = cnt[ln];
    int s[4];
    #pragma unroll
    for (int k = 0; k < 4; ++k) {
        int e = slot + 8 * k;
        int idx = (e < d) ? e : (d > 0 ? d - 1 : 0);
        s[k] = (int)sorted[(d > 0 ? st : 0) + idx];
    }
    float4 xv = ((const float4*)(x + ((size_t)node << 5)))[slot];
    ushort4 u[4];
    #pragma unroll
    for (int k = 0; k < 4; ++k) {
        if (8 * k < d)
            u[k] = *(const ushort4*)(yb + ((size_t)s[k] << 5) + (li << 2));
    }

    while (true) {
        // prefetch next node's state AND issue its y loads (full-iteration cover)
        const int ln_n   = ln + 8;
        const int node_n = node + 8;
        const bool have_n = (ln_n < NPB) && (node_n < n_nodes);
        int st_n = 0, d_n = 0;
        int sn[4];
        ushort4 un[4];
        float4 xv_n = make_float4(0.f, 0.f, 0.f, 0.f);
        if (have_n) {
            st_n = ex[ln_n];
            d_n  = cnt[ln_n];
            #pragma unroll
            for (int k = 0; k < 4; ++k) {
                int e = slot + 8 * k;
                int idx = (e < d_n) ? e : (d_n > 0 ? d_n - 1 : 0);
                sn[k] = (int)sorted[(d_n > 0 ? st_n : 0) + idx];
            }
            xv_n = ((const float4*)(x + ((size_t)node_n << 5)))[slot];
            #pragma unroll
            for (int k = 0; k < 4; ++k) {
                if (8 * k < d_n)
                    un[k] = *(const ushort4*)(yb + ((size_t)sn[k] << 5) + (li << 2));
            }
        }

        // W2 matvec partials (k in [4slot,4slot+4)) — VALU under load shadow
        float a0, a1, a2, a3;
        a0 = xv.x * w2t[0][0] + xv.y * w2t[1][0] + xv.z * w2t[2][0] + xv.w * w2t[3][0];
        a1 = xv.x * w2t[0][1] + xv.y * w2t[1][1] + xv.z * w2t[2][1] + xv.w * w2t[3][1];
        a2 = xv.x * w2t[0][2] + xv.y * w2t[1][2] + xv.z * w2t[2][2] + xv.w * w2t[3][2];
        a3 = xv.x * w2t[0][3] + xv.y * w2t[1][3] + xv.z * w2t[2][3] + xv.w * w2t[3][3];

        // consume u[] — issued a FULL iteration ago
        #pragma unroll
        for (int k = 0; k < 4; ++k) {
            if (8 * k < d) {
                const bool v = (slot + 8 * k) < d;
                a0 += v ? __uint_as_float((unsigned)u[k].x << 16) : 0.f;
                a1 += v ? __uint_as_float((unsigned)u[k].y << 16) : 0.f;
                a2 += v ? __uint_as_float((unsigned)u[k].z << 16) : 0.f;
                a3 += v ? __uint_as_float((unsigned)u[k].w << 16) : 0.f;
            }
        }
        // rare tail: degree > 32 (direct loads)
        for (int e0 = 32 + slot; e0 < d; e0 += 8) {
            int ss = (int)sorted[st + e0];
            ushort4 uu = *(const ushort4*)(yb + ((size_t)ss << 5) + (li << 2));
            a0 += __uint_as_float((unsigned)uu.x << 16);
            a1 += __uint_as_float((unsigned)uu.y << 16);
            a2 += __uint_as_float((unsigned)uu.z << 16);
            a3 += __uint_as_float((unsigned)uu.w << 16);
        }

        #pragma unroll
        for (int m = 8; m < 64; m <<= 1) {
            a0 += __shfl_xor(a0, m);
            a1 += __shfl_xor(a1, m);
            a2 += __shfl_xor(a2, m);
            a3 += __shfl_xor(a3, m);
        }

        if (slot == 0) {
            float4 w;
            w.x = a0 + bias.x;
            w.y = a1 + bias.y;
            w.z = a2 + bias.z;
            w.w = a3 + bias.w;
            ((float4*)(out + ((size_t)node << 5)))[li] = w;   // single write, no RMW
        }

        if (!have_n) break;
        ln = ln_n; node = node_n; st = st_n; d = d_n;
        s[0] = sn[0]; s[1] = sn[1]; s[2] = sn[2]; s[3] = sn[3];
        u[0] = un[0]; u[1] = un[1]; u[2] = un[2]; u[3] = un[3];
        xv = xv_n;
    }
}

extern "C" void kernel_launch(void* const* d_in, const int* in_sizes, int n_in,
                              void* d_out, int out_size, void* d_ws, size_t ws_size,
                              hipStream_t stream) {
    const float* x  = (const float*)d_in[0];
    const float* W1 = (const float*)d_in[1];
    const float* W2 = (const float*)d_in[2];
    const float* b2 = (const float*)d_in[3];
    const int*   ei = (const int*)d_in[4];

    const int n_nodes = in_sizes[0] / DIM;   // 100000
    const int n_edges = in_sizes[4] / 2;     // 1,600,000
    const int* src = ei;
    const int* dst = ei + n_edges;
    float* out = (float*)d_out;

    const int nb = (n_nodes + NPB - 1) / NPB;    // 782

    char* basep = (char*)d_ws;
    size_t off = 0;
    auto alloc = [&](size_t bytes) {
        char* p = basep + off;
        off = (off + bytes + 255) & ~(size_t)255;
        return p;
    };
    unsigned* y32    = (unsigned*)alloc((size_t)n_nodes * DIM * sizeof(unsigned short));
    int*      cursor = (int*)     alloc((size_t)nb * sizeof(int));
    unsigned* bedges = (unsigned*)alloc((size_t)nb * CAP * sizeof(unsigned));
    (void)ws_size;

    lin_y_kernel<<<1024, 256, 0, stream>>>(x, W1, y32, cursor, nb, n_nodes);
    bucket_scatter_kernel<<<(n_edges + EPB - 1) / EPB, 1024, 0, stream>>>(src, dst, cursor, bedges, n_edges);
    sort_gather_kernel<<<nb, 512, 0, stream>>>(cursor, bedges, (const unsigned short*)y32,
                                               x, W2, b2, out, n_nodes);
}

// Round 23
// 75.579 us; speedup vs baseline: 1.1140x; 1.0780x over previous
//
#include <hip/hip_runtime.h>
#include <hip/hip_bf16.h>

#define DIM 32
#define LOG_NPB 6
#define NPB 64               // nodes per bucket
#define CAP 2048             // edge capacity per bucket (avg ~1023, ~32 sigma)
#define NBINS 1600           // >= ceil(100000/64)=1563
#define EPB 16384            // edges per scatter block
#define EPT 16               // edges per thread in scatter (EPB/1024)

// ---------------------------------------------------------------------------
// Kernel 1: y = x @ W1^T (bf16 packed) ONLY. W1 row held in registers.
// Block 0 also inits bucket cursors (absolute: cursor[b] = b*CAP).
// ---------------------------------------------------------------------------
__global__ __launch_bounds__(256) void lin_y_kernel(
    const float* __restrict__ x,
    const float* __restrict__ W1,
    unsigned* __restrict__ y32,
    int* __restrict__ cursor, int nb,
    int n_nodes)
{
    __shared__ float xs[8][DIM];

    const int t = threadIdx.x;
    if (blockIdx.x == 0) {
        for (int i = t; i < nb; i += 256) cursor[i] = i * CAP;
    }

    const int r = t >> 5;
    const int c = t & 31;

    float4 w1r[8];
    #pragma unroll
    for (int q = 0; q < 8; ++q)
        w1r[q] = *(const float4*)(W1 + c * DIM + q * 4);

    const int ntiles = (n_nodes + 7) >> 3;

    for (int tile = blockIdx.x; tile < ntiles; tile += gridDim.x) {
        const int row = tile * 8 + r;
        __syncthreads();
        if (row < n_nodes) xs[r][c] = x[(long)row * DIM + c];
        __syncthreads();
        if (row < n_nodes) {
            const float4* xr = (const float4*)xs[r];
            float a1 = 0.0f;
            #pragma unroll
            for (int q = 0; q < 8; ++q) {
                float4 xv = xr[q];
                a1 += xv.x * w1r[q].x + xv.y * w1r[q].y + xv.z * w1r[q].z + xv.w * w1r[q].w;
            }
            float hi = __shfl_down(a1, 1);
            if ((c & 1) == 0) {
                __hip_bfloat16 blo = __float2bfloat16(a1);
                __hip_bfloat16 bhi = __float2bfloat16(hi);
                unsigned pack = ((unsigned)(*(unsigned short*)&bhi) << 16)
                              | (unsigned)(*(unsigned short*)&blo);
                y32[(size_t)row * 16 + (c >> 1)] = pack;
            }
        }
    }
}

// ---------------------------------------------------------------------------
// Pass 1: bucket scatter (98 fat blocks, rank merged into histogram atomic).
// ---------------------------------------------------------------------------
__global__ __launch_bounds__(1024) void bucket_scatter_kernel(
    const int* __restrict__ src, const int* __restrict__ dst,
    int* __restrict__ cursor, unsigned* __restrict__ bedges, int nE)
{
    __shared__ int cnt[NBINS];
    __shared__ int base[NBINS];

    const int t = threadIdx.x;
    const long blockStart = (long)blockIdx.x * EPB;

    for (int i = t; i < NBINS; i += 1024) cnt[i] = 0;
    __syncthreads();

    int es[EPT], ed[EPT], rk[EPT];
    #pragma unroll
    for (int i = 0; i < EPT; ++i) {
        long e = blockStart + (long)i * 1024 + t;
        if (e < nE) { es[i] = src[e]; ed[i] = dst[e]; }
        else        { es[i] = -1;     ed[i] = 0;      }
    }
    #pragma unroll
    for (int i = 0; i < EPT; ++i) {
        if (es[i] >= 0) rk[i] = atomicAdd(&cnt[ed[i] >> LOG_NPB], 1);
    }
    __syncthreads();

    for (int i = t; i < NBINS; i += 1024) {
        int c = cnt[i];
        if (c > 0) base[i] = atomicAdd(&cursor[i], c);
    }
    __syncthreads();

    #pragma unroll
    for (int i = 0; i < EPT; ++i) {
        if (es[i] >= 0) {
            int b = ed[i] >> LOG_NPB;
            int p = base[b] + rk[i];
            if (p < (b + 1) * CAP)
                bedges[p] = ((unsigned)es[i] << LOG_NPB) | (unsigned)(ed[i] & (NPB - 1));
        }
    }
}

// ---------------------------------------------------------------------------
// Pass 2 (fused): per-bucket LDS sort + pipelined gather + W2 skip.
// NPB=64: 1563 blocks (~6/CU -> full occupancy ceiling), ~17 KB LDS,
// sort phases over ~1024 edges, 64-bin single-wave scan, each wave walks
// 8 nodes. Gather pipeline identical to r20 (1-deep, proven).
// ---------------------------------------------------------------------------
__global__ __launch_bounds__(512) void sort_gather_kernel(
    const int* __restrict__ cursor, const unsigned* __restrict__ bedges,
    const unsigned short* __restrict__ yb,
    const float* __restrict__ x,
    const float* __restrict__ W2,
    const float* __restrict__ b2,
    float* __restrict__ out, int n_nodes)
{
    __shared__ unsigned ent[CAP];      // 8 KB raw entries
    __shared__ unsigned sorted[CAP];   // 8 KB src ids sorted by local dst
    __shared__ int cnt[NPB];
    __shared__ int ex[NPB];
    __shared__ int cur[NPB];

    const int b = blockIdx.x;
    const int t = threadIdx.x;
    const int wv   = t >> 6;      // wave 0..7
    const int lane = t & 63;
    const int slot = lane >> 3;   // 0..7: edge slot / k-quad
    const int li   = lane & 7;    // output dims li*4..li*4+3

    // per-lane W2^T tile + bias
    float w2t[4][4];
    #pragma unroll
    for (int j = 0; j < 4; ++j)
        #pragma unroll
        for (int k = 0; k < 4; ++k)
            w2t[k][j] = W2[(size_t)(4 * li + j) * DIM + 4 * slot + k];
    const float4 bias = ((const float4*)b2)[li];

    const int start = b * CAP;
    int n = cursor[b] - start;
    if (n > CAP) n = CAP;
    if (n < 0) n = 0;

    if (t < NPB) { cnt[t] = 0; cur[t] = 0; }
    __syncthreads();

    for (int i = t; i < n; i += 512) {
        unsigned e = bedges[start + i];
        ent[i] = e;
        atomicAdd(&cnt[e & (NPB - 1)], 1);
    }
    __syncthreads();

    // single-wave exclusive scan over 64 bins (1 bin/lane, no barriers)
    if (t < 64) {
        int c0 = cnt[t];
        int v  = c0;
        #pragma unroll
        for (int off = 1; off < 64; off <<= 1) {
            int u = __shfl_up(v, off);
            if (t >= off) v += u;
        }
        ex[t] = v - c0;
    }
    __syncthreads();

    for (int i = t; i < n; i += 512) {
        unsigned e = ent[i];
        int bin = (int)(e & (NPB - 1));
        int r = atomicAdd(&cur[bin], 1);
        sorted[ex[bin] + r] = e >> LOG_NPB;
    }
    __syncthreads();

    // ---- pipelined gather + skip phase (r20 form, 1-deep) ----
    int ln   = wv;
    int node = b * NPB + ln;
    if (node >= n_nodes) return;

    int st = ex[ln];
    int d  = cnt[ln];
    int s[4];
    #pragma unroll
    for (int k = 0; k < 4; ++k) {
        int e = slot + 8 * k;
        int idx = (e < d) ? e : (d > 0 ? d - 1 : 0);
        s[k] = (int)sorted[(d > 0 ? st : 0) + idx];
    }
    float4 xv = ((const float4*)(x + ((size_t)node << 5)))[slot];

    while (true) {
        // issue current node's y loads (chunk k only if 8k < d, wave-uniform)
        ushort4 u[4];
        #pragma unroll
        for (int k = 0; k < 4; ++k) {
            if (8 * k < d)
                u[k] = *(const ushort4*)(yb + ((size_t)s[k] << 5) + (li << 2));
        }

        // prefetch next node's state while y loads are in flight
        const int ln_n   = ln + 8;
        const int node_n = node + 8;
        const bool have_n = (ln_n < NPB) && (node_n < n_nodes);
        int st_n = 0, d_n = 0;
        int sn[4];
        float4 xv_n = make_float4(0.f, 0.f, 0.f, 0.f);
        if (have_n) {
            st_n = ex[ln_n];
            d_n  = cnt[ln_n];
            #pragma unroll
            for (int k = 0; k < 4; ++k) {
                int e = slot + 8 * k;
                int idx = (e < d_n) ? e : (d_n > 0 ? d_n - 1 : 0);
                sn[k] = (int)sorted[(d_n > 0 ? st_n : 0) + idx];
            }
            xv_n = ((const float4*)(x + ((size_t)node_n << 5)))[slot];
        }

        // W2 matvec partials (k in [4slot,4slot+4)) — VALU under load shadow
        float a0, a1, a2, a3;
        a0 = xv.x * w2t[0][0] + xv.y * w2t[1][0] + xv.z * w2t[2][0] + xv.w * w2t[3][0];
        a1 = xv.x * w2t[0][1] + xv.y * w2t[1][1] + xv.z * w2t[2][1] + xv.w * w2t[3][1];
        a2 = xv.x * w2t[0][2] + xv.y * w2t[1][2] + xv.z * w2t[2][2] + xv.w * w2t[3][2];
        a3 = xv.x * w2t[0][3] + xv.y * w2t[1][3] + xv.z * w2t[2][3] + xv.w * w2t[3][3];

        // gather adds
        #pragma unroll
        for (int k = 0; k < 4; ++k) {
            if (8 * k < d) {
                const bool v = (slot + 8 * k) < d;
                a0 += v ? __uint_as_float((unsigned)u[k].x << 16) : 0.f;
                a1 += v ? __uint_as_float((unsigned)u[k].y << 16) : 0.f;
                a2 += v ? __uint_as_float((unsigned)u[k].z << 16) : 0.f;
                a3 += v ? __uint_as_float((unsigned)u[k].w << 16) : 0.f;
            }
        }
        // rare tail: degree > 32
        for (int e0 = 32 + slot; e0 < d; e0 += 8) {
            int ss = (int)sorted[st + e0];
            ushort4 uu = *(const ushort4*)(yb + ((size_t)ss << 5) + (li << 2));
            a0 += __uint_as_float((unsigned)uu.x << 16);
            a1 += __uint_as_float((unsigned)uu.y << 16);
            a2 += __uint_as_float((unsigned)uu.z << 16);
            a3 += __uint_as_float((unsigned)uu.w << 16);
        }

        #pragma unroll
        for (int m = 8; m < 64; m <<= 1) {
            a0 += __shfl_xor(a0, m);
            a1 += __shfl_xor(a1, m);
            a2 += __shfl_xor(a2, m);
            a3 += __shfl_xor(a3, m);
        }

        if (slot == 0) {
            float4 w;
            w.x = a0 + bias.x;
            w.y = a1 + bias.y;
            w.z = a2 + bias.z;
            w.w = a3 + bias.w;
            ((float4*)(out + ((size_t)node << 5)))[li] = w;   // single write, no RMW
        }

        if (!have_n) break;
        ln = ln_n; node = node_n; st = st_n; d = d_n;
        s[0] = sn[0]; s[1] = sn[1]; s[2] = sn[2]; s[3] = sn[3];
        xv = xv_n;
    }
}

extern "C" void kernel_launch(void* const* d_in, const int* in_sizes, int n_in,
                              void* d_out, int out_size, void* d_ws, size_t ws_size,
                              hipStream_t stream) {
    const float* x  = (const float*)d_in[0];
    const float* W1 = (const float*)d_in[1];
    const float* W2 = (const float*)d_in[2];
    const float* b2 = (const float*)d_in[3];
    const int*   ei = (const int*)d_in[4];

    const int n_nodes = in_sizes[0] / DIM;   // 100000
    const int n_edges = in_sizes[4] / 2;     // 1,600,000
    const int* src = ei;
    const int* dst = ei + n_edges;
    float* out = (float*)d_out;

    const int nb = (n_nodes + NPB - 1) / NPB;    // 1563

    char* basep = (char*)d_ws;
    size_t off = 0;
    auto alloc = [&](size_t bytes) {
        char* p = basep + off;
        off = (off + bytes + 255) & ~(size_t)255;
        return p;
    };
    unsigned* y32    = (unsigned*)alloc((size_t)n_nodes * DIM * sizeof(unsigned short));
    int*      cursor = (int*)     alloc((size_t)nb * sizeof(int));
    unsigned* bedges = (unsigned*)alloc((size_t)nb * CAP * sizeof(unsigned));
    (void)ws_size;

    lin_y_kernel<<<1024, 256, 0, stream>>>(x, W1, y32, cursor, nb, n_nodes);
    bucket_scatter_kernel<<<(n_edges + EPB - 1) / EPB, 1024, 0, stream>>>(src, dst, cursor, bedges, n_edges);
    sort_gather_kernel<<<nb, 512, 0, stream>>>(cursor, bedges, (const unsigned short*)y32,
                                               x, W2, b2, out, n_nodes);
}

// Round 24
// 75.210 us; speedup vs baseline: 1.1195x; 1.0049x over previous
//
#include <hip/hip_runtime.h>
#include <hip/hip_bf16.h>

#define DIM 32
#define LOG_NPB 6
#define NPB 64               // nodes per bucket
#define CAP 2048             // edge capacity per bucket (avg ~1023, ~32 sigma)
#define NBINS 1600           // >= ceil(100000/64)=1563
#define EPB 16384            // edges per scatter block
#define EPT 16               // edges per thread in scatter (EPB/1024)

// ---------------------------------------------------------------------------
// Kernel 1: y = x @ W1^T (bf16 packed) ONLY. W1 row held in registers.
// Block 0 also inits bucket cursors (absolute: cursor[b] = b*CAP).
// ---------------------------------------------------------------------------
__global__ __launch_bounds__(256) void lin_y_kernel(
    const float* __restrict__ x,
    const float* __restrict__ W1,
    unsigned* __restrict__ y32,
    int* __restrict__ cursor, int nb,
    int n_nodes)
{
    __shared__ float xs[8][DIM];

    const int t = threadIdx.x;
    if (blockIdx.x == 0) {
        for (int i = t; i < nb; i += 256) cursor[i] = i * CAP;
    }

    const int r = t >> 5;
    const int c = t & 31;

    float4 w1r[8];
    #pragma unroll
    for (int q = 0; q < 8; ++q)
        w1r[q] = *(const float4*)(W1 + c * DIM + q * 4);

    const int ntiles = (n_nodes + 7) >> 3;

    for (int tile = blockIdx.x; tile < ntiles; tile += gridDim.x) {
        const int row = tile * 8 + r;
        __syncthreads();
        if (row < n_nodes) xs[r][c] = x[(long)row * DIM + c];
        __syncthreads();
        if (row < n_nodes) {
            const float4* xr = (const float4*)xs[r];
            float a1 = 0.0f;
            #pragma unroll
            for (int q = 0; q < 8; ++q) {
                float4 xv = xr[q];
                a1 += xv.x * w1r[q].x + xv.y * w1r[q].y + xv.z * w1r[q].z + xv.w * w1r[q].w;
            }
            float hi = __shfl_down(a1, 1);
            if ((c & 1) == 0) {
                __hip_bfloat16 blo = __float2bfloat16(a1);
                __hip_bfloat16 bhi = __float2bfloat16(hi);
                unsigned pack = ((unsigned)(*(unsigned short*)&bhi) << 16)
                              | (unsigned)(*(unsigned short*)&blo);
                y32[(size_t)row * 16 + (c >> 1)] = pack;
            }
        }
    }
}

// ---------------------------------------------------------------------------
// Pass 1: bucket scatter (98 fat blocks, rank merged into histogram atomic).
// ---------------------------------------------------------------------------
__global__ __launch_bounds__(1024) void bucket_scatter_kernel(
    const int* __restrict__ src, const int* __restrict__ dst,
    int* __restrict__ cursor, unsigned* __restrict__ bedges, int nE)
{
    __shared__ int cnt[NBINS];
    __shared__ int base[NBINS];

    const int t = threadIdx.x;
    const long blockStart = (long)blockIdx.x * EPB;

    for (int i = t; i < NBINS; i += 1024) cnt[i] = 0;
    __syncthreads();

    int es[EPT], ed[EPT], rk[EPT];
    #pragma unroll
    for (int i = 0; i < EPT; ++i) {
        long e = blockStart + (long)i * 1024 + t;
        if (e < nE) { es[i] = src[e]; ed[i] = dst[e]; }
        else        { es[i] = -1;     ed[i] = 0;      }
    }
    #pragma unroll
    for (int i = 0; i < EPT; ++i) {
        if (es[i] >= 0) rk[i] = atomicAdd(&cnt[ed[i] >> LOG_NPB], 1);
    }
    __syncthreads();

    for (int i = t; i < NBINS; i += 1024) {
        int c = cnt[i];
        if (c > 0) base[i] = atomicAdd(&cursor[i], c);
    }
    __syncthreads();

    #pragma unroll
    for (int i = 0; i < EPT; ++i) {
        if (es[i] >= 0) {
            int b = ed[i] >> LOG_NPB;
            int p = base[b] + rk[i];
            if (p < (b + 1) * CAP)
                bedges[p] = ((unsigned)es[i] << LOG_NPB) | (unsigned)(ed[i] & (NPB - 1));
        }
    }
}

// ---------------------------------------------------------------------------
// Pass 2 (fused): per-bucket sort + pipelined gather + W2 skip.
// Sort phase now REGISTER-STAGED with rank-merged histogram (r13 trick):
// each thread holds <=4 packed edges in registers, rank = hist atomicAdd
// return, sorted[] written directly after the 64-bin single-wave scan.
// No ent[] array, no cur[] rank pass. LDS ~8.7 KB.
// Gather pipeline identical to r23 (1-deep, proven).
// ---------------------------------------------------------------------------
__global__ __launch_bounds__(512) void sort_gather_kernel(
    const int* __restrict__ cursor, const unsigned* __restrict__ bedges,
    const unsigned short* __restrict__ yb,
    const float* __restrict__ x,
    const float* __restrict__ W2,
    const float* __restrict__ b2,
    float* __restrict__ out, int n_nodes)
{
    __shared__ unsigned sorted[CAP];   // 8 KB src ids sorted by local dst
    __shared__ int cnt[NPB];
    __shared__ int ex[NPB];

    const int b = blockIdx.x;
    const int t = threadIdx.x;
    const int wv   = t >> 6;      // wave 0..7
    const int lane = t & 63;
    const int slot = lane >> 3;   // 0..7: edge slot / k-quad
    const int li   = lane & 7;    // output dims li*4..li*4+3

    // per-lane W2^T tile + bias
    float w2t[4][4];
    #pragma unroll
    for (int j = 0; j < 4; ++j)
        #pragma unroll
        for (int k = 0; k < 4; ++k)
            w2t[k][j] = W2[(size_t)(4 * li + j) * DIM + 4 * slot + k];
    const float4 bias = ((const float4*)b2)[li];

    const int start = b * CAP;
    int n = cursor[b] - start;
    if (n > CAP) n = CAP;
    if (n < 0) n = 0;

    if (t < NPB) cnt[t] = 0;
    __syncthreads();

    // register-staged load + rank-merged histogram (stride-512 coalesced)
    unsigned pk[4];
    int rk[4];
    #pragma unroll
    for (int i = 0; i < 4; ++i) {
        int idx = t + i * 512;
        if (idx < n) {
            pk[i] = bedges[start + idx];
            rk[i] = atomicAdd(&cnt[pk[i] & (NPB - 1)], 1);
        } else pk[i] = 0xFFFFFFFFu;
    }
    __syncthreads();

    // single-wave exclusive scan over 64 bins (1 bin/lane, no barriers)
    if (t < 64) {
        int c0 = cnt[t];
        int v  = c0;
        #pragma unroll
        for (int off = 1; off < 64; off <<= 1) {
            int u = __shfl_up(v, off);
            if (t >= off) v += u;
        }
        ex[t] = v - c0;
    }
    __syncthreads();

    // direct scatter from registers
    #pragma unroll
    for (int i = 0; i < 4; ++i) {
        if (pk[i] != 0xFFFFFFFFu)
            sorted[ex[pk[i] & (NPB - 1)] + rk[i]] = pk[i] >> LOG_NPB;
    }
    __syncthreads();

    // ---- pipelined gather + skip phase (r20/r23 form, 1-deep) ----
    int ln   = wv;
    int node = b * NPB + ln;
    if (node >= n_nodes) return;

    int st = ex[ln];
    int d  = cnt[ln];
    int s[4];
    #pragma unroll
    for (int k = 0; k < 4; ++k) {
        int e = slot + 8 * k;
        int idx = (e < d) ? e : (d > 0 ? d - 1 : 0);
        s[k] = (int)sorted[(d > 0 ? st : 0) + idx];
    }
    float4 xv = ((const float4*)(x + ((size_t)node << 5)))[slot];

    while (true) {
        // issue current node's y loads (chunk k only if 8k < d, wave-uniform)
        ushort4 u[4];
        #pragma unroll
        for (int k = 0; k < 4; ++k) {
            if (8 * k < d)
                u[k] = *(const ushort4*)(yb + ((size_t)s[k] << 5) + (li << 2));
        }

        // prefetch next node's state while y loads are in flight
        const int ln_n   = ln + 8;
        const int node_n = node + 8;
        const bool have_n = (ln_n < NPB) && (node_n < n_nodes);
        int st_n = 0, d_n = 0;
        int sn[4];
        float4 xv_n = make_float4(0.f, 0.f, 0.f, 0.f);
        if (have_n) {
            st_n = ex[ln_n];
            d_n  = cnt[ln_n];
            #pragma unroll
            for (int k = 0; k < 4; ++k) {
                int e = slot + 8 * k;
                int idx = (e < d_n) ? e : (d_n > 0 ? d_n - 1 : 0);
                sn[k] = (int)sorted[(d_n > 0 ? st_n : 0) + idx];
            }
            xv_n = ((const float4*)(x + ((size_t)node_n << 5)))[slot];
        }

        // W2 matvec partials (k in [4slot,4slot+4)) — VALU under load shadow
        float a0, a1, a2, a3;
        a0 = xv.x * w2t[0][0] + xv.y * w2t[1][0] + xv.z * w2t[2][0] + xv.w * w2t[3][0];
        a1 = xv.x * w2t[0][1] + xv.y * w2t[1][1] + xv.z * w2t[2][1] + xv.w * w2t[3][1];
        a2 = xv.x * w2t[0][2] + xv.y * w2t[1][2] + xv.z * w2t[2][2] + xv.w * w2t[3][2];
        a3 = xv.x * w2t[0][3] + xv.y * w2t[1][3] + xv.z * w2t[2][3] + xv.w * w2t[3][3];

        // gather adds
        #pragma unroll
        for (int k = 0; k < 4; ++k) {
            if (8 * k < d) {
                const bool v = (slot + 8 * k) < d;
                a0 += v ? __uint_as_float((unsigned)u[k].x << 16) : 0.f;
                a1 += v ? __uint_as_float((unsigned)u[k].y << 16) : 0.f;
                a2 += v ? __uint_as_float((unsigned)u[k].z << 16) : 0.f;
                a3 += v ? __uint_as_float((unsigned)u[k].w << 16) : 0.f;
            }
        }
        // rare tail: degree > 32
        for (int e0 = 32 + slot; e0 < d; e0 += 8) {
            int ss = (int)sorted[st + e0];
            ushort4 uu = *(const ushort4*)(yb + ((size_t)ss << 5) + (li << 2));
            a0 += __uint_as_float((unsigned)uu.x << 16);
            a1 += __uint_as_float((unsigned)uu.y << 16);
            a2 += __uint_as_float((unsigned)uu.z << 16);
            a3 += __uint_as_float((unsigned)uu.w << 16);
        }

        #pragma unroll
        for (int m = 8; m < 64; m <<= 1) {
            a0 += __shfl_xor(a0, m);
            a1 += __shfl_xor(a1, m);
            a2 += __shfl_xor(a2, m);
            a3 += __shfl_xor(a3, m);
        }

        if (slot == 0) {
            float4 w;
            w.x = a0 + bias.x;
            w.y = a1 + bias.y;
            w.z = a2 + bias.z;
            w.w = a3 + bias.w;
            ((float4*)(out + ((size_t)node << 5)))[li] = w;   // single write, no RMW
        }

        if (!have_n) break;
        ln = ln_n; node = node_n; st = st_n; d = d_n;
        s[0] = sn[0]; s[1] = sn[1]; s[2] = sn[2]; s[3] = sn[3];
        xv = xv_n;
    }
}

extern "C" void kernel_launch(void* const* d_in, const int* in_sizes, int n_in,
                              void* d_out, int out_size, void* d_ws, size_t ws_size,
                              hipStream_t stream) {
    const float* x  = (const float*)d_in[0];
    const float* W1 = (const float*)d_in[1];
    const float* W2 = (const float*)d_in[2];
    const float* b2 = (const float*)d_in[3];
    const int*   ei = (const int*)d_in[4];

    const int n_nodes = in_sizes[0] / DIM;   // 100000
    const int n_edges = in_sizes[4] / 2;     // 1,600,000
    const int* src = ei;
    const int* dst = ei + n_edges;
    float* out = (float*)d_out;

    const int nb = (n_nodes + NPB - 1) / NPB;    // 1563

    char* basep = (char*)d_ws;
    size_t off = 0;
    auto alloc = [&](size_t bytes) {
        char* p = basep + off;
        off = (off + bytes + 255) & ~(size_t)255;
        return p;
    };
    unsigned* y32    = (unsigned*)alloc((size_t)n_nodes * DIM * sizeof(unsigned short));
    int*      cursor = (int*)     alloc((size_t)nb * sizeof(int));
    unsigned* bedges = (unsigned*)alloc((size_t)nb * CAP * sizeof(unsigned));
    (void)ws_size;

    lin_y_kernel<<<1024, 256, 0, stream>>>(x, W1, y32, cursor, nb, n_nodes);
    bucket_scatter_kernel<<<(n_edges + EPB - 1) / EPB, 1024, 0, stream>>>(src, dst, cursor, bedges, n_edges);
    sort_gather_kernel<<<nb, 512, 0, stream>>>(cursor, bedges, (const unsigned short*)y32,
                                               x, W2, b2, out, n_nodes);
}